// Round 8
// baseline (82.384 us; speedup 1.0000x reference)
//
#include <hip/hip_runtime.h>
#include <hip/hip_bf16.h>

// Problem constants
#define Bn   4
#define Cn   64
#define Hn   96
#define Wn   96
#define Gn   4
#define CGn  16      // Cn / Gn
#define KKn  9
#define NOFF 18      // 2*K*K offset channels
#define HWn  (Hn*Wn) // 9216

// ws layout (floats)
#define OFF_BASE  0                        // B*HW*18 pos-major offsets (663552)
#define WT_BASE   (Bn*HWn*NOFF)            // wT[ci][o][k]  (10368)
#define WMF_BASE  (WT_BASE + Cn*NOFF*KKn)  // bf16 MFMA A-frag weights: 10240 bf16 = 5120 fl
#define XT_BASE   (WMF_BASE + 5120)        // xT[b][pos][c] NHWC (2359296)

typedef __attribute__((ext_vector_type(8))) short short8v;   // 8 bf16 = 4 VGPR
typedef __attribute__((ext_vector_type(4))) float f32x4;

__device__ inline short f2bs(float v) {
    __hip_bfloat16 h = __float2bfloat16(v);
    return *reinterpret_cast<short*>(&h);
}

// ---------------------------------------------------------------------------
// Kernel 0 (fused): blocks [0,576) transpose x NCHW->NHWC; rest reorder
// offset-conv weights (fp32) and pack deform weights into bf16 MFMA A-frags.
// ---------------------------------------------------------------------------
#define NTRB (Bn * (HWn / 64))   // 576 transpose blocks
__global__ __launch_bounds__(256) void prep_all(
    const float* __restrict__ x, const float* __restrict__ w_off,
    const float* __restrict__ w_def, float* __restrict__ ws)
{
    __shared__ float t[64][65];
    if (blockIdx.x < NTRB) {
        const int nb = HWn / 64;               // 144
        const int b  = blockIdx.x / nb;
        const int p0 = (blockIdx.x % nb) * 64;
        float* xT = ws + XT_BASE;
        for (int i = threadIdx.x; i < 64 * 64; i += 256) {
            const int c = i >> 6, l = i & 63;
            t[c][l] = x[(b * Cn + c) * HWn + p0 + l];
        }
        __syncthreads();
        for (int i = threadIdx.x; i < 64 * 64; i += 256) {
            const int l = i >> 6, c = i & 63;
            xT[(b * HWn + p0 + l) * Cn + c] = t[c][l];
        }
        return;
    }
    const int i = (blockIdx.x - NTRB) * 256 + threadIdx.x;
    const int NT = Cn * NOFF * KKn;        // 10368
    const int NW = Gn * 5 * CGn * 4 * 8;   // 10240 bf16 elements
    if (i < NT) {
        const int ci = i / (NOFF * KKn);
        const int r  = i % (NOFF * KKn);
        const int o  = r / KKn, k = r % KKn;
        ws[WT_BASE + i] = w_off[(o * Cn + ci) * KKn + k];
    } else if (i < NT + NW) {
        const int j  = i - NT;
        const int jj = j & 7;
        const int q  = (j >> 3) & 3;
        const int d  = (j >> 5) & 15;
        const int kp = (j >> 9) % 5;
        const int g  = j / 2560;
        const int tt = jj & 1;
        const int c  = 4 * q + (jj >> 1);
        const int k  = 2 * kp + tt;
        const float v = (k < KKn) ? w_def[((g * CGn + d) * CGn + c) * KKn + k] : 0.f;
        ((__hip_bfloat16*)(ws + WMF_BASE))[j] = __float2bfloat16(v);
    }
}

// ---------------------------------------------------------------------------
// Kernel 1: offset conv (64 -> 18, 3x3, pad 1), ci-split across 8 waves.
// XCD-swizzled. Writes offsets POS-MAJOR: offs[(b*HW+pos)*18 + o].
// ---------------------------------------------------------------------------
#define OCB 64
__global__ __launch_bounds__(512) void offset_conv_v3(
    const float* __restrict__ x, const float* __restrict__ ws,
    const float* __restrict__ bias, float* __restrict__ offs)
{
    __shared__ float red[8][OCB][NOFF + 1];
    const float* __restrict__ wT = ws + WT_BASE;

    const int bid  = (blockIdx.x & 7) * 72 + (blockIdx.x >> 3);
    const int wave = threadIdx.x >> 6;
    const int lane = threadIdx.x & 63;
    const int nb   = HWn / OCB;            // 144
    const int b    = bid / nb;
    const int pbase= (bid % nb) * OCB;
    const int pos  = pbase + lane;
    const int ho = pos / Wn, wo = pos % Wn;

    float acc[NOFF];
    #pragma unroll
    for (int o = 0; o < NOFF; o++) acc[o] = 0.f;

    const float* xb = x + b * Cn * HWn;
    const int ci0 = __builtin_amdgcn_readfirstlane(wave * 8);

    for (int ci = ci0; ci < ci0 + 8; ci++) {
        const float* xc = xb + ci * HWn;
        float xv[KKn];
        #pragma unroll
        for (int ki = 0; ki < 3; ki++) {
            const int y = ho - 1 + ki;
            const bool vy = (y >= 0) && (y < Hn);
            const float* xr = xc + y * Wn;
            #pragma unroll
            for (int kj = 0; kj < 3; kj++) {
                const int xx = wo - 1 + kj;
                const bool v = vy && (xx >= 0) && (xx < Wn);
                xv[ki * 3 + kj] = v ? xr[xx] : 0.f;
            }
        }
        const float* wp = wT + ci * (NOFF * KKn);   // wave-uniform
        #pragma unroll
        for (int o = 0; o < NOFF; o++) {
            #pragma unroll
            for (int k = 0; k < KKn; k++)
                acc[o] += xv[k] * wp[o * KKn + k];
        }
    }

    #pragma unroll
    for (int o = 0; o < NOFF; o++) red[wave][lane][o] = acc[o];
    __syncthreads();

    for (int idx = threadIdx.x; idx < NOFF * OCB; idx += 512) {
        const int o = idx % NOFF;
        const int p = idx / NOFF;
        float s = bias[o];
        #pragma unroll
        for (int w2 = 0; w2 < 8; w2++) s += red[w2][p][o];
        offs[(b * HWn + pbase + p) * NOFF + o] = s;
    }
}

// ---------------------------------------------------------------------------
// Kernel 2: deformable conv via MFMA, max-MLP version. Wave = 16-pos tile.
// Lane l: pr = l&15 (pos / A-row d), q = l>>4 (kappa quad).
// All 36 corner gathers issued via inline-asm global_load_dwordx4 (voffset +
// SGPR base) so the allocator cannot re-sink them; ONE s_waitcnt vmcnt(0) +
// sched_barrier(0) fence, then bilinear combine + 5 MFMAs.
// ---------------------------------------------------------------------------
#define GLOAD4(dst, off_) \
    asm volatile("global_load_dwordx4 %0, %1, %2" \
                 : "=v"(dst) : "v"(off_), "s"(xbase))

__global__ __launch_bounds__(256) void deform_v8(
    const float* __restrict__ ws, float* __restrict__ out)
{
    const float* __restrict__ off2 = ws + OFF_BASE;
    const float* __restrict__ xT   = ws + XT_BASE;
    const short8v* __restrict__ wmf = (const short8v*)(ws + WMF_BASE);

    // grid = 2304 = 8 * 288: XCD k gets 288 consecutive work ids (2 bg)
    const int bid = (blockIdx.x & 7) * 288 + (blockIdx.x >> 3);
    const int nbb = HWn / 64;              // 144 blocks per (b,g)
    const int bg  = bid / nbb;
    const int g   = bg & (Gn - 1);
    const int b   = bg >> 2;
    const int wave = threadIdx.x >> 6;
    const int lane = threadIdx.x & 63;
    const int pr   = lane & 15;            // pos-sub (B-col) / d (A-row)
    const int q    = lane >> 4;            // kappa quad
    const int pos0 = (bid % nbb) * 64 + wave * 16;
    const int pos  = pos0 + pr;
    const int ho = pos / Wn, wo = pos % Wn;

    // offsets for this pos (compiler loads; drained before asm region)
    const float2* op2 = (const float2*)(off2 + (b * HWn + pos) * NOFF);
    float2 o2[KKn];
    #pragma unroll
    for (int k = 0; k < KKn; k++) o2[k] = op2[k];

    // preload 5 A-fragments of weights (d = pr, quad = q)
    short8v a[5];
    #pragma unroll
    for (int kp = 0; kp < 5; kp++)
        a[kp] = wmf[((g * 5 + kp) * CGn + pr) * 4 + q];

    const float* xbase = xT + (size_t)b * HWn * Cn;          // wave-uniform
    const unsigned choff = (unsigned)(g * CGn + q * 4) * 4u; // channel byte off

    // phase 1: all 9 taps' bilinear weights + 36 byte-voffsets, issue loads
    float  cwt[KKn][4];
    f32x4  dat[KKn][4];
    #pragma unroll
    for (int k = 0; k < KKn; k++) {
        const int ki = k / 3, kj = k % 3;
        const float ysf = (float)(ho - 1 + ki) + o2[k].x;
        const float xsf = (float)(wo - 1 + kj) + o2[k].y;
        const float y0f = floorf(ysf), x0f = floorf(xsf);
        const int   y0  = (int)y0f,    x0  = (int)x0f;
        const float wy1 = ysf - y0f, wx1 = xsf - x0f;
        const float wy0 = 1.f - wy1, wx0 = 1.f - wx1;

        const bool vy0 = (y0 >= 0)  && (y0 < Hn);
        const bool vy1 = (y0 >= -1) && (y0 < Hn - 1);
        const bool vx0 = (x0 >= 0)  && (x0 < Wn);
        const bool vx1 = (x0 >= -1) && (x0 < Wn - 1);

        const int cy0 = min(max(y0,     0), Hn - 1);
        const int cy1 = min(max(y0 + 1, 0), Hn - 1);
        const int cx0 = min(max(x0,     0), Wn - 1);
        const int cx1 = min(max(x0 + 1, 0), Wn - 1);

        cwt[k][0] = wy0 * wx0 * ((vy0 && vx0) ? 1.f : 0.f);
        cwt[k][1] = wy0 * wx1 * ((vy0 && vx1) ? 1.f : 0.f);
        cwt[k][2] = wy1 * wx0 * ((vy1 && vx0) ? 1.f : 0.f);
        cwt[k][3] = wy1 * wx1 * ((vy1 && vx1) ? 1.f : 0.f);

        const unsigned v00 = (unsigned)(cy0 * Wn + cx0) * (Cn * 4u) + choff;
        const unsigned v01 = (unsigned)(cy0 * Wn + cx1) * (Cn * 4u) + choff;
        const unsigned v10 = (unsigned)(cy1 * Wn + cx0) * (Cn * 4u) + choff;
        const unsigned v11 = (unsigned)(cy1 * Wn + cx1) * (Cn * 4u) + choff;

        GLOAD4(dat[k][0], v00);
        GLOAD4(dat[k][1], v01);
        GLOAD4(dat[k][2], v10);
        GLOAD4(dat[k][3], v11);
    }

    // one wait for all 36 loads; fence against hoisting consumers (rule #18)
    asm volatile("s_waitcnt vmcnt(0)" ::: "memory");
    __builtin_amdgcn_sched_barrier(0);

    // phase 2: bilinear combine + MFMA contraction
    f32x4 acc = {0.f, 0.f, 0.f, 0.f};
    #pragma unroll
    for (int kp = 0; kp < 5; kp++) {
        const int k0 = 2 * kp;
        float s0[4], s1[4];
        #pragma unroll
        for (int c = 0; c < 4; c++)
            s0[c] = cwt[k0][0] * dat[k0][0][c] + cwt[k0][1] * dat[k0][1][c]
                  + cwt[k0][2] * dat[k0][2][c] + cwt[k0][3] * dat[k0][3][c];
        if (kp < 4) {
            const int k1 = k0 + 1;
            #pragma unroll
            for (int c = 0; c < 4; c++)
                s1[c] = cwt[k1][0] * dat[k1][0][c] + cwt[k1][1] * dat[k1][1][c]
                      + cwt[k1][2] * dat[k1][2][c] + cwt[k1][3] * dat[k1][3][c];
        } else {
            s1[0] = s1[1] = s1[2] = s1[3] = 0.f;
        }
        short8v bfr;
        bfr[0] = f2bs(s0[0]); bfr[1] = f2bs(s1[0]);
        bfr[2] = f2bs(s0[1]); bfr[3] = f2bs(s1[1]);
        bfr[4] = f2bs(s0[2]); bfr[5] = f2bs(s1[2]);
        bfr[6] = f2bs(s0[3]); bfr[7] = f2bs(s1[3]);
        acc = __builtin_amdgcn_mfma_f32_16x16x32_bf16(a[kp], bfr, acc, 0, 0, 0);
    }

    // D: col = lane&15 = pos-sub, row = q*4 + r = d
    float* op = out + (b * Cn + g * CGn) * HWn + pos0;
    #pragma unroll
    for (int r = 0; r < 4; r++) {
        const int d = q * 4 + r;
        op[d * HWn + pr] = acc[r];
    }
}

// ---------------------------------------------------------------------------
extern "C" void kernel_launch(void* const* d_in, const int* in_sizes, int n_in,
                              void* d_out, int out_size, void* d_ws, size_t ws_size,
                              hipStream_t stream) {
    const float* x     = (const float*)d_in[0];
    const float* w_off = (const float*)d_in[1];
    const float* b_off = (const float*)d_in[2];
    const float* w_def = (const float*)d_in[3];
    float* out = (float*)d_out;
    float* ws  = (float*)d_ws;

    const int n_prep = Cn * NOFF * KKn + Gn * 5 * CGn * 4 * 8;  // 20608
    const int nblk = NTRB + (n_prep + 255) / 256;               // 576 + 81

    prep_all<<<nblk, 256, 0, stream>>>(x, w_off, w_def, ws);

    offset_conv_v3<<<Bn * (HWn / OCB), 512, 0, stream>>>(x, ws, b_off, ws + OFF_BASE);

    deform_v8<<<Bn * Gn * (HWn / 64), 256, 0, stream>>>(ws, out);
}

// Round 9
// 51.397 us; speedup vs baseline: 1.6029x; 1.6029x over previous
//
#include <hip/hip_runtime.h>
#include <hip/hip_bf16.h>

// Problem constants
#define Bn   4
#define Cn   64
#define Hn   96
#define Wn   96
#define Gn   4
#define CGn  16      // Cn / Gn
#define KKn  9
#define NOFF 18      // 2*K*K offset channels
#define HWn  (Hn*Wn) // 9216

// ws layout (floats)
#define OFF_BASE  0                        // B*HW*18 pos-major offsets (663552)
#define WT_BASE   (Bn*HWn*NOFF)            // wT[ci][o][k]  (10368)
#define WMF_BASE  (WT_BASE + Cn*NOFF*KKn)  // bf16 MFMA A-frag weights: 10240 bf16
#define XG_BASE   (WMF_BASE + 5120)        // bf16 xg[b][g][pos][16] : 2359296 shorts

typedef __attribute__((ext_vector_type(8))) short short8v;   // 8 bf16 = 4 VGPR
typedef __attribute__((ext_vector_type(4))) float f32x4;
typedef __attribute__((ext_vector_type(4))) unsigned int uint4v;
typedef unsigned short ushort_t;

__device__ inline short f2bs(float v) {
    __hip_bfloat16 h = __float2bfloat16(v);
    return *reinterpret_cast<short*>(&h);
}

// ---------------------------------------------------------------------------
// Kernel 0 (fused): blocks [0,576) transpose x NCHW -> bf16 xg[b][g][pos][c];
// rest: reorder offset-conv weights (fp32) + pack deform weights into bf16
// A-frags with kappa = ch + 16*tap:  lane(d=row, q): j -> c=(q&1)*8+j,
// k = 2*kp + (q>>1); zero-pad k=9.
// ---------------------------------------------------------------------------
#define NTRB (Bn * (HWn / 64))   // 576 transpose blocks
__global__ __launch_bounds__(256) void prep_all(
    const float* __restrict__ x, const float* __restrict__ w_off,
    const float* __restrict__ w_def, float* __restrict__ ws)
{
    __shared__ float t[64][65];
    if (blockIdx.x < NTRB) {
        const int nb = HWn / 64;               // 144
        const int b  = blockIdx.x / nb;
        const int p0 = (blockIdx.x % nb) * 64;
        __hip_bfloat16* xg = (__hip_bfloat16*)(ws + XG_BASE);
        for (int i = threadIdx.x; i < 64 * 64; i += 256) {
            const int c = i >> 6, l = i & 63;
            t[c][l] = x[(b * Cn + c) * HWn + p0 + l];
        }
        __syncthreads();
        for (int i = threadIdx.x; i < 64 * 64; i += 256) {
            const int l = i >> 6, c = i & 63;
            const int g = c >> 4, cc = c & 15;
            xg[((size_t)(b * Gn + g) * HWn + p0 + l) * CGn + cc] =
                __float2bfloat16(t[c][l]);
        }
        return;
    }
    const int i = (blockIdx.x - NTRB) * 256 + threadIdx.x;
    const int NT = Cn * NOFF * KKn;        // 10368
    const int NW = Gn * 5 * CGn * 4 * 8;   // 10240 bf16 elements
    if (i < NT) {
        const int ci = i / (NOFF * KKn);
        const int r  = i % (NOFF * KKn);
        const int o  = r / KKn, k = r % KKn;
        ws[WT_BASE + i] = w_off[(o * Cn + ci) * KKn + k];
    } else if (i < NT + NW) {
        const int j  = i - NT;
        const int jj = j & 7;
        const int q  = (j >> 3) & 3;
        const int d  = (j >> 5) & 15;
        const int kp = (j >> 9) % 5;
        const int g  = j / 2560;
        const int c  = (q & 1) * 8 + jj;
        const int k  = 2 * kp + (q >> 1);
        const float v = (k < KKn) ? w_def[((g * CGn + d) * CGn + c) * KKn + k] : 0.f;
        ((__hip_bfloat16*)(ws + WMF_BASE))[j] = __float2bfloat16(v);
    }
}

// ---------------------------------------------------------------------------
// Kernel 1: offset conv (64 -> 18, 3x3, pad 1), ci-split across 8 waves.
// XCD-swizzled. Writes offsets POS-MAJOR: offs[(b*HW+pos)*18 + o].
// ---------------------------------------------------------------------------
#define OCB 64
__global__ __launch_bounds__(512) void offset_conv_v3(
    const float* __restrict__ x, const float* __restrict__ ws,
    const float* __restrict__ bias, float* __restrict__ offs)
{
    __shared__ float red[8][OCB][NOFF + 1];
    const float* __restrict__ wT = ws + WT_BASE;

    const int bid  = (blockIdx.x & 7) * 72 + (blockIdx.x >> 3);
    const int wave = threadIdx.x >> 6;
    const int lane = threadIdx.x & 63;
    const int nb   = HWn / OCB;            // 144
    const int b    = bid / nb;
    const int pbase= (bid % nb) * OCB;
    const int pos  = pbase + lane;
    const int ho = pos / Wn, wo = pos % Wn;

    float acc[NOFF];
    #pragma unroll
    for (int o = 0; o < NOFF; o++) acc[o] = 0.f;

    const float* xb = x + b * Cn * HWn;
    const int ci0 = __builtin_amdgcn_readfirstlane(wave * 8);

    for (int ci = ci0; ci < ci0 + 8; ci++) {
        const float* xc = xb + ci * HWn;
        float xv[KKn];
        #pragma unroll
        for (int ki = 0; ki < 3; ki++) {
            const int y = ho - 1 + ki;
            const bool vy = (y >= 0) && (y < Hn);
            const float* xr = xc + y * Wn;
            #pragma unroll
            for (int kj = 0; kj < 3; kj++) {
                const int xx = wo - 1 + kj;
                const bool v = vy && (xx >= 0) && (xx < Wn);
                xv[ki * 3 + kj] = v ? xr[xx] : 0.f;
            }
        }
        const float* wp = wT + ci * (NOFF * KKn);   // wave-uniform
        #pragma unroll
        for (int o = 0; o < NOFF; o++) {
            #pragma unroll
            for (int k = 0; k < KKn; k++)
                acc[o] += xv[k] * wp[o * KKn + k];
        }
    }

    #pragma unroll
    for (int o = 0; o < NOFF; o++) red[wave][lane][o] = acc[o];
    __syncthreads();

    for (int idx = threadIdx.x; idx < NOFF * OCB; idx += 512) {
        const int o = idx % NOFF;
        const int p = idx / NOFF;
        float s = bias[o];
        #pragma unroll
        for (int w2 = 0; w2 < 8; w2++) s += red[w2][p][o];
        offs[(b * HWn + pbase + p) * NOFF + o] = s;
    }
}

// ---------------------------------------------------------------------------
// Kernel 2: deformable conv via MFMA, kappa = ch + 16*tap.
// Wave = 16 pos. Lane l: pr = l&15 (pos / A-row d), q = l>>4,
// half = q&1 (channel octet), tp = q>>1 (tap parity).
// Per tap-PAIR: 4 corner loads per lane (dwordx4 = its own 8 bf16 channels
// of ITS tap's corner pixel) -> 18 gather instrs/wave total (half of v7/v8).
// 3-pair pipeline with counted vmcnt(8/8/8/4/0) + sched_barrier (rule #18).
// ---------------------------------------------------------------------------
#define GLOAD4(dst, off_) \
    asm volatile("global_load_dwordx4 %0, %1, %2" \
                 : "=v"(dst) : "v"(off_), "s"(xgb))

__global__ __launch_bounds__(256) void deform_v9(
    const float* __restrict__ ws, float* __restrict__ out)
{
    const float* __restrict__ off2 = ws + OFF_BASE;
    const short8v* __restrict__ wmf = (const short8v*)(ws + WMF_BASE);

    // grid = 2304 = 8 * 288: XCD k gets 288 consecutive work ids (2 bg)
    const int bid = (blockIdx.x & 7) * 288 + (blockIdx.x >> 3);
    const int nbb = HWn / 64;              // 144 blocks per (b,g)
    const int bg  = bid / nbb;
    const int g   = bg & (Gn - 1);
    const int b   = bg >> 2;
    const int wave = threadIdx.x >> 6;
    const int lane = threadIdx.x & 63;
    const int pr   = lane & 15;            // pos-sub (B-col) / d (A-row)
    const int q    = lane >> 4;
    const int half = q & 1;                // channel octet
    const int tp   = q >> 1;               // tap parity
    const int pos0 = (bid % nbb) * 64 + wave * 16;
    const int pos  = pos0 + pr;
    const int ho = pos / Wn, wo = pos % Wn;

    // offsets: lane needs taps {2kp + tp}
    const float2* op2 = (const float2*)(off2 + (b * HWn + pos) * NOFF);
    float2 o2[5];
    #pragma unroll
    for (int kp = 0; kp < 5; kp++) {
        int kk = 2 * kp + tp; if (kk > 8) kk = 8;   // tap9 -> dummy (cwt zeroed)
        o2[kp] = op2[kk];
    }
    // A-frag weights
    short8v a[5];
    #pragma unroll
    for (int kp = 0; kp < 5; kp++)
        a[kp] = wmf[((g * 5 + kp) * CGn + pr) * 4 + q];

    const ushort_t* xgb = (const ushort_t*)(ws + XG_BASE)
                        + (size_t)(b * Gn + g) * HWn * CGn;
    const unsigned hoff = (unsigned)half * 16u;

    // materialize compiler loads, then zero the vm counter so the counted
    // waits below see ONLY the asm gathers
    #pragma unroll
    for (int kp = 0; kp < 5; kp++) {
        asm volatile("" : "+v"(o2[kp].x), "+v"(o2[kp].y));
        asm volatile("" : "+v"(a[kp]));
    }
    asm volatile("s_waitcnt vmcnt(0)" ::: "memory");
    __builtin_amdgcn_sched_barrier(0);

    float cwt[5][4];
    f32x4 dat[5][4];

#define PAIRSETUP(KP)                                                      \
  {                                                                        \
    const int k  = 2 * (KP) + tp;                                          \
    const int ki = k / 3, kj = k - 3 * ki;                                 \
    const float m = (k <= 8) ? 1.f : 0.f;                                  \
    const float ysf = (float)(ho - 1 + ki) + o2[KP].x;                     \
    const float xsf = (float)(wo - 1 + kj) + o2[KP].y;                     \
    const float y0f = floorf(ysf), x0f = floorf(xsf);                      \
    const int   y0  = (int)y0f,    x0  = (int)x0f;                         \
    const float wy1 = ysf - y0f, wx1 = xsf - x0f;                          \
    const float wy0 = 1.f - wy1, wx0 = 1.f - wx1;                          \
    const bool vy0 = (y0 >= 0)  && (y0 < Hn);                              \
    const bool vy1 = (y0 >= -1) && (y0 < Hn - 1);                          \
    const bool vx0 = (x0 >= 0)  && (x0 < Wn);                              \
    const bool vx1 = (x0 >= -1) && (x0 < Wn - 1);                          \
    const int cy0 = min(max(y0,     0), Hn - 1);                           \
    const int cy1 = min(max(y0 + 1, 0), Hn - 1);                           \
    const int cx0 = min(max(x0,     0), Wn - 1);                           \
    const int cx1 = min(max(x0 + 1, 0), Wn - 1);                           \
    cwt[KP][0] = m * wy0 * wx0 * ((vy0 && vx0) ? 1.f : 0.f);               \
    cwt[KP][1] = m * wy0 * wx1 * ((vy0 && vx1) ? 1.f : 0.f);               \
    cwt[KP][2] = m * wy1 * wx0 * ((vy1 && vx0) ? 1.f : 0.f);               \
    cwt[KP][3] = m * wy1 * wx1 * ((vy1 && vx1) ? 1.f : 0.f);               \
    const unsigned v00 = (unsigned)(cy0 * Wn + cx0) * 32u + hoff;          \
    const unsigned v01 = (unsigned)(cy0 * Wn + cx1) * 32u + hoff;          \
    const unsigned v10 = (unsigned)(cy1 * Wn + cx0) * 32u + hoff;          \
    const unsigned v11 = (unsigned)(cy1 * Wn + cx1) * 32u + hoff;          \
    GLOAD4(dat[KP][0], v00);                                               \
    GLOAD4(dat[KP][1], v01);                                               \
    GLOAD4(dat[KP][2], v10);                                               \
    GLOAD4(dat[KP][3], v11);                                               \
  }

    PAIRSETUP(0); PAIRSETUP(1); PAIRSETUP(2);

    f32x4 acc = {0.f, 0.f, 0.f, 0.f};

    #pragma unroll
    for (int kp = 0; kp < 5; kp++) {
        // outstanding before wait: 3 pairs (kp<=2), 2 (kp==3), 1 (kp==4)
        if (kp <= 2)      asm volatile("s_waitcnt vmcnt(8)" ::: "memory");
        else if (kp == 3) asm volatile("s_waitcnt vmcnt(4)" ::: "memory");
        else              asm volatile("s_waitcnt vmcnt(0)" ::: "memory");
        __builtin_amdgcn_sched_barrier(0);

        float s[8] = {0.f,0.f,0.f,0.f,0.f,0.f,0.f,0.f};
        #pragma unroll
        for (int c4 = 0; c4 < 4; c4++) {
            const float w = cwt[kp][c4];
            const uint4v u = *reinterpret_cast<const uint4v*>(&dat[kp][c4]);
            #pragma unroll
            for (int w2 = 0; w2 < 4; w2++) {
                unsigned lo = u[w2] << 16;
                unsigned hi = u[w2] & 0xffff0000u;
                s[2*w2]   += w * *reinterpret_cast<float*>(&lo);
                s[2*w2+1] += w * *reinterpret_cast<float*>(&hi);
            }
        }
        short8v fr;
        #pragma unroll
        for (int j = 0; j < 8; j++) fr[j] = f2bs(s[j]);
        acc = __builtin_amdgcn_mfma_f32_16x16x32_bf16(a[kp], fr, acc, 0, 0, 0);

        if (kp == 0) PAIRSETUP(3);
        if (kp == 1) PAIRSETUP(4);
    }

    // D: col = lane&15 = pos-sub, row = q*4 + r = d
    float* op = out + (b * Cn + g * CGn) * HWn + pos0;
    #pragma unroll
    for (int r = 0; r < 4; r++)
        op[(q * 4 + r) * HWn + pr] = acc[r];
}

// ---------------------------------------------------------------------------
extern "C" void kernel_launch(void* const* d_in, const int* in_sizes, int n_in,
                              void* d_out, int out_size, void* d_ws, size_t ws_size,
                              hipStream_t stream) {
    const float* x     = (const float*)d_in[0];
    const float* w_off = (const float*)d_in[1];
    const float* b_off = (const float*)d_in[2];
    const float* w_def = (const float*)d_in[3];
    float* out = (float*)d_out;
    float* ws  = (float*)d_ws;

    const int n_prep = Cn * NOFF * KKn + Gn * 5 * CGn * 4 * 8;  // 20608
    const int nblk = NTRB + (n_prep + 255) / 256;               // 576 + 81

    prep_all<<<nblk, 256, 0, stream>>>(x, w_off, w_def, ws);

    offset_conv_v3<<<Bn * (HWn / OCB), 512, 0, stream>>>(x, ws, b_off, ws + OFF_BASE);

    deform_v9<<<Bn * Gn * (HWn / 64), 256, 0, stream>>>(ws, out);
}